// Round 1
// baseline (180.949 us; speedup 1.0000x reference)
//
#include <hip/hip_runtime.h>
#include <math.h>

// Problem constants (fixed by setup_inputs)
#define Nn 32
#define Cc 128
#define Ss 4096
#define Kk 64
#define NCHUNK 16
#define SCHUNK (Ss / NCHUNK)   // 256 pixels per block
#define ST 64                  // pixels per subtile
#define NSUB (SCHUNK / ST)     // 4 subtiles per block
#define BLK 256
#define XSTR 68                // x_lds row stride (floats): 16B-aligned, bank-friendly
#define ASTR 68                // a_lds row stride (floats): 16B-aligned

// Fused: per-pixel L2-norm -> 1x1 conv logits -> softmax -> VLAD partial GEMM.
// vlad[n][k][c] partials and asum[n][k] accumulated via atomicAdd into d_ws.
__global__ __launch_bounds__(BLK, 2) void netvlad_main(
    const float* __restrict__ x,
    const float* __restrict__ conv_w,
    const float* __restrict__ conv_b,
    float* __restrict__ vlad,
    float* __restrict__ asum)
{
    __shared__ __align__(16) float x_lds[Cc * XSTR];  // [c][s]  128x68
    __shared__ __align__(16) float a_lds[ST * ASTR];  // [s][k]  64x68
    __shared__ float red_m[ST][4];
    __shared__ float red_s[ST][4];
    __shared__ float invn[ST];

    const int t  = threadIdx.x;
    const int n  = blockIdx.y;
    const int kg = t >> 4;     // 0..15 : k = 4*kg+kk (logits & vlad)
    const int sg = t & 15;     // 0..15 : s = 4*sg+ss (logits); c = sg+16j (vlad)
    const int p  = t >> 2;     // 0..63 pixel (norm / softmax)
    const int ii = t & 3;      // 0..3

    float acc[4][8];           // vlad partials: [kk][cj]
#pragma unroll
    for (int a1 = 0; a1 < 4; ++a1)
#pragma unroll
        for (int b1 = 0; b1 < 8; ++b1) acc[a1][b1] = 0.f;
    float asum_part[16];       // raw softmax sums for k = ii+4j
#pragma unroll
    for (int j = 0; j < 16; ++j) asum_part[j] = 0.f;

    const float* xn = x + (size_t)n * Cc * Ss;

    for (int sub = 0; sub < NSUB; ++sub) {
        const int s0 = blockIdx.x * SCHUNK + sub * ST;
        __syncthreads();  // prior subtile's vlad reads of x_lds/a_lds done

        // ---- stage x tile: 128 c x 64 s (float4, coalesced 64B runs) ----
#pragma unroll
        for (int r = 0; r < 8; ++r) {
            int idx4 = t + BLK * r;            // 0..2047 float4s
            int c    = idx4 >> 4;              // 0..127
            int sq   = (idx4 & 15) << 2;       // 0..60
            float4 v = *(const float4*)(xn + (size_t)c * Ss + s0 + sq);
            *(float4*)&x_lds[c * XSTR + sq] = v;
        }
        __syncthreads();

        // ---- per-pixel inverse norm over C ----
        {
            float ssq = 0.f;
#pragma unroll
            for (int j = 0; j < 32; ++j) {
                float v = x_lds[(ii + 4 * j) * XSTR + p];
                ssq += v * v;
            }
            red_m[p][ii] = ssq;
        }
        __syncthreads();
        if (ii == 0) {
            float tot = red_m[p][0] + red_m[p][1] + red_m[p][2] + red_m[p][3];
            invn[p] = 1.0f / fmaxf(sqrtf(tot), 1e-12f);
        }
        __syncthreads();

        // ---- logits: l[kk][ss] = sum_c w[k][c]*x[c][s];  4k x 4s per thread ----
        {
            float l[4][4];
#pragma unroll
            for (int a1 = 0; a1 < 4; ++a1)
#pragma unroll
                for (int b1 = 0; b1 < 4; ++b1) l[a1][b1] = 0.f;

#pragma unroll 4
            for (int c0 = 0; c0 < Cc; c0 += 4) {
                float wv[4][4];
#pragma unroll
                for (int kk = 0; kk < 4; ++kk) {
                    float4 w4 = *(const float4*)(conv_w + (4 * kg + kk) * Cc + c0);
                    wv[kk][0] = w4.x; wv[kk][1] = w4.y; wv[kk][2] = w4.z; wv[kk][3] = w4.w;
                }
                float xv[4][4];
#pragma unroll
                for (int cc = 0; cc < 4; ++cc) {
                    float4 x4 = *(const float4*)&x_lds[(c0 + cc) * XSTR + 4 * sg];
                    xv[cc][0] = x4.x; xv[cc][1] = x4.y; xv[cc][2] = x4.z; xv[cc][3] = x4.w;
                }
#pragma unroll
                for (int kk = 0; kk < 4; ++kk)
#pragma unroll
                    for (int ss2 = 0; ss2 < 4; ++ss2)
#pragma unroll
                        for (int cc = 0; cc < 4; ++cc)
                            l[kk][ss2] += wv[kk][cc] * xv[cc][ss2];
            }
            // epilogue: scale by invn (x was raw), add bias, write raw logits
            float binv[4];
#pragma unroll
            for (int ss2 = 0; ss2 < 4; ++ss2) binv[ss2] = invn[4 * sg + ss2];
            float bk[4];
#pragma unroll
            for (int kk = 0; kk < 4; ++kk) bk[kk] = conv_b[4 * kg + kk];
#pragma unroll
            for (int ss2 = 0; ss2 < 4; ++ss2) {
                float4 o;
                o.x = l[0][ss2] * binv[ss2] + bk[0];
                o.y = l[1][ss2] * binv[ss2] + bk[1];
                o.z = l[2][ss2] * binv[ss2] + bk[2];
                o.w = l[3][ss2] * binv[ss2] + bk[3];
                *(float4*)&a_lds[(4 * sg + ss2) * ASTR + 4 * kg] = o;
            }
        }
        __syncthreads();

        // ---- softmax over k per pixel p; thread covers k = ii + 4j ----
        {
            float l[16];
#pragma unroll
            for (int j = 0; j < 16; ++j) l[j] = a_lds[p * ASTR + ii + 4 * j];
            float m = l[0];
#pragma unroll
            for (int j = 1; j < 16; ++j) m = fmaxf(m, l[j]);
            red_m[p][ii] = m;
            __syncthreads();
            float m4 = fmaxf(fmaxf(red_m[p][0], red_m[p][1]),
                             fmaxf(red_m[p][2], red_m[p][3]));
            float e[16];
            float ls = 0.f;
#pragma unroll
            for (int j = 0; j < 16; ++j) { e[j] = __expf(l[j] - m4); ls += e[j]; }
            red_s[p][ii] = ls;
            __syncthreads();
            float tot  = red_s[p][0] + red_s[p][1] + red_s[p][2] + red_s[p][3];
            float itot = 1.0f / tot;
            float sca  = itot * invn[p];   // fold invn: a' = a * invn -> a'*x = a*xf
#pragma unroll
            for (int j = 0; j < 16; ++j) {
                asum_part[j] += e[j] * itot;               // raw a for centroid term
                a_lds[p * ASTR + ii + 4 * j] = e[j] * sca; // a' for vlad GEMM
            }
        }
        __syncthreads();

        // ---- vlad accumulate: acc[kk][j] += a'[s][4kg+kk] * x[sg+16j][s] ----
#pragma unroll 4
        for (int s = 0; s < ST; ++s) {
            float4 a4 = *(const float4*)&a_lds[s * ASTR + 4 * kg];
            float av[4] = {a4.x, a4.y, a4.z, a4.w};
            float xv[8];
#pragma unroll
            for (int j = 0; j < 8; ++j) xv[j] = x_lds[(sg + 16 * j) * XSTR + s];
#pragma unroll
            for (int kk = 0; kk < 4; ++kk)
#pragma unroll
                for (int j = 0; j < 8; ++j) acc[kk][j] += av[kk] * xv[j];
        }
    }

    // ---- commit vlad partials (16 chunk-blocks contend per address) ----
    float* vbase = vlad + ((size_t)n * Kk + 4 * kg) * Cc + sg;
#pragma unroll
    for (int kk = 0; kk < 4; ++kk)
#pragma unroll
        for (int j = 0; j < 8; ++j)
            atomicAdd(vbase + kk * Cc + 16 * j, acc[kk][j]);

    // ---- block-reduce asum then one atomic per k ----
    __syncthreads();  // a_lds dead now
#pragma unroll
    for (int j = 0; j < 16; ++j) a_lds[p * ASTR + ii + 4 * j] = asum_part[j];
    __syncthreads();
    if (t < Kk) {
        float s_ = 0.f;
        for (int p2 = 0; p2 < ST; ++p2) s_ += a_lds[p2 * ASTR + t];
        atomicAdd(&asum[n * Kk + t], s_);
    }
}

// centroid subtract -> intra-normalize over c -> FC over k. One wave per n.
__global__ __launch_bounds__(64) void netvlad_final(
    const float* __restrict__ vlad, const float* __restrict__ asum,
    const float* __restrict__ centroids, const float* __restrict__ fc_w,
    float* __restrict__ out)
{
    const int n = blockIdx.x;
    const int t = threadIdx.x;   // 64 threads; each owns c=t and c=t+64
    float o0 = 0.f, o1 = 0.f;
    for (int k = 0; k < Kk; ++k) {
        float as = asum[n * Kk + k];
        float fk = fc_w[k];
        const float* vr = vlad + ((size_t)n * Kk + k) * Cc;
        const float* cr = centroids + k * Cc;
        float v0 = vr[t]      - as * cr[t];
        float v1 = vr[t + 64] - as * cr[t + 64];
        float ssq = v0 * v0 + v1 * v1;
#pragma unroll
        for (int off = 32; off > 0; off >>= 1)
            ssq += __shfl_xor(ssq, off, 64);
        float sc = fk / fmaxf(sqrtf(ssq), 1e-12f);
        o0 += v0 * sc;
        o1 += v1 * sc;
    }
    out[n * Cc + t]      = o0;
    out[n * Cc + t + 64] = o1;
}

extern "C" void kernel_launch(void* const* d_in, const int* in_sizes, int n_in,
                              void* d_out, int out_size, void* d_ws, size_t ws_size,
                              hipStream_t stream) {
    (void)in_sizes; (void)n_in; (void)out_size; (void)ws_size;
    const float* x         = (const float*)d_in[0];
    const float* conv_w    = (const float*)d_in[1];
    const float* conv_b    = (const float*)d_in[2];
    const float* centroids = (const float*)d_in[3];
    const float* fc_w      = (const float*)d_in[4];
    float* out = (float*)d_out;

    float* vlad = (float*)d_ws;                         // [N][K][C] = 1 MB
    float* asum = vlad + (size_t)Nn * Kk * Cc;          // [N][K]    = 8 KB
    size_t zero_bytes = ((size_t)Nn * Kk * Cc + (size_t)Nn * Kk) * sizeof(float);
    hipMemsetAsync(d_ws, 0, zero_bytes, stream);        // ws is poisoned 0xAA each call

    dim3 grid(NCHUNK, Nn);
    netvlad_main<<<grid, BLK, 0, stream>>>(x, conv_w, conv_b, vlad, asum);
    netvlad_final<<<Nn, 64, 0, stream>>>(vlad, asum, centroids, fc_w, out);
}